// Round 1
// baseline (448.347 us; speedup 1.0000x reference)
//
#include <hip/hip_runtime.h>
#include <hip/hip_bf16.h>

typedef __attribute__((ext_vector_type(4))) float f32x4;
typedef __attribute__((ext_vector_type(8))) short short8;

static constexpr int BB = 32;
static constexpr int SEQ = 1024;
static constexpr int DIM = 1024;

__device__ __forceinline__ ushort f2bf(float f) {
  union { float f; uint u; } x; x.f = f;
  uint r = x.u + 0x7fffu + ((x.u >> 16) & 1u);
  return (ushort)(r >> 16);
}
__device__ __forceinline__ float bf2f(ushort h) {
  union { uint u; float f; } x; x.u = ((uint)h) << 16; return x.f;
}

// async global->LDS, 16B per lane. LDS dest is wave-uniform-base + lane*16.
__device__ __forceinline__ void async16(const void* g, void* l) {
  __builtin_amdgcn_global_load_lds(
      (const __attribute__((address_space(1))) unsigned int*)g,
      (__attribute__((address_space(3))) unsigned int*)l, 16, 0, 0);
}

// fp32 -> bf16 elementwise (vectorized by 4)
__global__ void cvt_kernel(const float* __restrict__ in, ushort* __restrict__ out, long n4) {
  long i = (long)blockIdx.x * blockDim.x + threadIdx.x;
  const long stride = (long)gridDim.x * blockDim.x;
  for (; i < n4; i += stride) {
    float4 v = reinterpret_cast<const float4*>(in)[i];
    ushort4 o = make_ushort4(f2bf(v.x), f2bf(v.y), f2bf(v.z), f2bf(v.w));
    reinterpret_cast<ushort4*>(out)[i] = o;
  }
}

// C[m,n] = scale * sum_k A[m,k]*Bt[n,k] (+ bias[n]); A:[M][K] Bt:[N][K] row-major bf16.
// 128x128 tile, BK=32, 256 threads (4 waves 2x2, each 64x64 = 4x4 frags of 16x16x32).
template<int OUT_BF16, int HAS_BIAS>
__global__ void gemm_bt(const ushort* __restrict__ A, const ushort* __restrict__ Bt,
                        void* __restrict__ Cv, const float* __restrict__ bias,
                        int M, int N, int K, float scale,
                        long sA, long sB, long sC)
{
  __shared__ ushort As[2][128 * 32];
  __shared__ ushort Bs[2][128 * 32];

  const int t = threadIdx.x;
  const int z = blockIdx.z;
  const ushort* Ab = A + (long)z * sA;
  const ushort* Bb = Bt + (long)z * sB;
  const int tm = blockIdx.y * 128;
  const int tn = blockIdx.x * 128;

  const int l  = t & 63;
  const int w  = t >> 6;
  const int wm = (w >> 1) * 64;
  const int wn = (w & 1) * 64;
  const int fr = l & 15;        // row-in-frag (A) / col-in-frag (B,C)
  const int ke = (l >> 4) * 8;  // k element offset within BK for frag load

  f32x4 acc[4][4];
#pragma unroll
  for (int i = 0; i < 4; ++i)
#pragma unroll
    for (int j = 0; j < 4; ++j) acc[i][j] = {0.f, 0.f, 0.f, 0.f};

  auto stage = [&](int buf, int k0) {
#pragma unroll
    for (int it = 0; it < 2; ++it) {
      const int idx = t + it * 256;        // 0..511 -> LDS byte idx*16 (thread-linear)
      const int r   = idx >> 2;            // 0..127 tile row
      const int kb  = (idx & 3) * 8;       // 0,8,16,24 elems
      async16(Ab + (long)(tm + r) * K + (k0 + kb), &As[buf][idx * 8]);
      async16(Bb + (long)(tn + r) * K + (k0 + kb), &Bs[buf][idx * 8]);
    }
  };

  const int nk = K >> 5;
  stage(0, 0);
  __syncthreads();
  for (int kt = 0; kt < nk; ++kt) {
    const int buf = kt & 1;
    if (kt + 1 < nk) stage(buf ^ 1, (kt + 1) << 5);
    short8 af[4], bfr[4];
#pragma unroll
    for (int f = 0; f < 4; ++f) {
      af[f]  = *(const short8*)&As[buf][(wm + f * 16 + fr) * 32 + ke];
      bfr[f] = *(const short8*)&Bs[buf][(wn + f * 16 + fr) * 32 + ke];
    }
#pragma unroll
    for (int i = 0; i < 4; ++i)
#pragma unroll
      for (int j = 0; j < 4; ++j)
        acc[i][j] = __builtin_amdgcn_mfma_f32_16x16x32_bf16(af[i], bfr[j], acc[i][j], 0, 0, 0);
    __syncthreads();
  }

  // epilogue: C/D layout col=lane&15, row=(lane>>4)*4+reg  [verified m89/m91]
  const int cr = (l >> 4) * 4;
#pragma unroll
  for (int i = 0; i < 4; ++i) {
#pragma unroll
    for (int j = 0; j < 4; ++j) {
      const int row = tm + wm + i * 16 + cr;
      const int col = tn + wn + j * 16 + fr;
      const float bv = HAS_BIAS ? bias[col] : 0.0f;
#pragma unroll
      for (int r = 0; r < 4; ++r) {
        const float v = acc[i][j][r] * scale + bv;
        const long off = (long)z * sC + (long)(row + r) * N + col;
        if (OUT_BF16) ((ushort*)Cv)[off] = f2bf(v);
        else          ((float*)Cv)[off]  = v;
      }
    }
  }
}

// per-batch 64x64-tile bf16 transpose: out[z][d][s] = in[z][s][d]
__global__ void transpose_bt(const ushort* __restrict__ in, ushort* __restrict__ out) {
  const int z = blockIdx.z;
  const long off = (long)z * SEQ * DIM;
  in += off; out += off;
  __shared__ ushort tile[64][68];
  const int t = threadIdx.x;
  const int r0 = blockIdx.y * 64, c0 = blockIdx.x * 64;
  const int tr = t >> 4;
  const int tc = (t & 15) * 4;
#pragma unroll
  for (int it = 0; it < 4; ++it) {
    const int r = tr + it * 16;
    ushort4 v = *(const ushort4*)&in[(long)(r0 + r) * DIM + c0 + tc];
    *(ushort4*)&tile[r][tc] = v;
  }
  __syncthreads();
#pragma unroll
  for (int it = 0; it < 4; ++it) {
    const int dr = tr + it * 16;
    ushort4 v = make_ushort4(tile[tc + 0][dr], tile[tc + 1][dr],
                             tile[tc + 2][dr], tile[tc + 3][dr]);
    *(ushort4*)&out[(long)(c0 + dr) * SEQ + r0 + tc] = v;
  }
}

// softmax over BATCH dim (axis=0): for each (q,k), normalize across 32 batches.
// In-place on bf16 scores [B][S*S]; each thread owns 4 contiguous k elems.
__global__ void softmax_b(ushort* __restrict__ sc) {
  const long SSl = (long)SEQ * SEQ;
  const long e = ((long)blockIdx.x * blockDim.x + threadIdx.x) * 4;
  if (e >= SSl) return;
  uint2 raw[BB];
#pragma unroll
  for (int b = 0; b < BB; ++b) raw[b] = *(const uint2*)&sc[b * SSl + e];
  float mx[4] = {-3.0e38f, -3.0e38f, -3.0e38f, -3.0e38f};
#pragma unroll
  for (int b = 0; b < BB; ++b) {
    const uint lo = raw[b].x, hi = raw[b].y;
    mx[0] = fmaxf(mx[0], bf2f((ushort)(lo & 0xffffu)));
    mx[1] = fmaxf(mx[1], bf2f((ushort)(lo >> 16)));
    mx[2] = fmaxf(mx[2], bf2f((ushort)(hi & 0xffffu)));
    mx[3] = fmaxf(mx[3], bf2f((ushort)(hi >> 16)));
  }
  float sum[4] = {0.f, 0.f, 0.f, 0.f};
#pragma unroll
  for (int b = 0; b < BB; ++b) {
    const uint lo = raw[b].x, hi = raw[b].y;
    const float x0 = __expf(bf2f((ushort)(lo & 0xffffu)) - mx[0]);
    const float x1 = __expf(bf2f((ushort)(lo >> 16))     - mx[1]);
    const float x2 = __expf(bf2f((ushort)(hi & 0xffffu)) - mx[2]);
    const float x3 = __expf(bf2f((ushort)(hi >> 16))     - mx[3]);
    sum[0] += x0; sum[1] += x1; sum[2] += x2; sum[3] += x3;
    raw[b].x = (uint)f2bf(x0) | ((uint)f2bf(x1) << 16);
    raw[b].y = (uint)f2bf(x2) | ((uint)f2bf(x3) << 16);
  }
  const float r0 = 1.0f / sum[0], r1 = 1.0f / sum[1];
  const float r2 = 1.0f / sum[2], r3 = 1.0f / sum[3];
#pragma unroll
  for (int b = 0; b < BB; ++b) {
    const uint lo = raw[b].x, hi = raw[b].y;
    const uint o0 = f2bf(bf2f((ushort)(lo & 0xffffu)) * r0);
    const uint o1 = f2bf(bf2f((ushort)(lo >> 16))     * r1);
    const uint o2 = f2bf(bf2f((ushort)(hi & 0xffffu)) * r2);
    const uint o3 = f2bf(bf2f((ushort)(hi >> 16))     * r3);
    uint2 o; o.x = o0 | (o1 << 16); o.y = o2 | (o3 << 16);
    *(uint2*)&sc[b * SSl + e] = o;
  }
}

extern "C" void kernel_launch(void* const* d_in, const int* in_sizes, int n_in,
                              void* d_out, int out_size, void* d_ws, size_t ws_size,
                              hipStream_t stream) {
  const float* text = (const float*)d_in[0];
  const float* W    = (const float*)d_in[1];
  const float* bias = (const float*)d_in[2];
  float* out = (float*)d_out;

  const long nTxt = (long)BB * SEQ * DIM;   // 33,554,432
  const long nW   = (long)DIM * DIM;        // 1,048,576
  const long SSl  = (long)SEQ * SEQ;        // per-batch score elems

  char* ws = (char*)d_ws;
  ushort* qkv   = (ushort*)ws;                 // 64MB bf16 qkv [B][S][D]
  ushort* qkvT  = (ushort*)(ws + nTxt * 2);    // 64MB bf16 qkv^T [B][D][S]
  ushort* sc    = (ushort*)(ws + nTxt * 4);    // 64MB: text_bf16, then scores/attn
  ushort* textb = sc;                          // alias (text_bf16 dead after GEMM1)
  ushort* Wb    = (ushort*)(ws + nTxt * 6);    // 2MB bf16 W [D][D]
  if (ws_size < (size_t)(nTxt * 6 + nW * 2)) return;  // insufficient scratch -> fail visibly

  // 1. convert inputs to bf16
  cvt_kernel<<<2048, 256, 0, stream>>>(text, textb, nTxt / 4);
  cvt_kernel<<<256, 256, 0, stream>>>(W, Wb, nW / 4);
  // 2. qkv = text @ W.T + b   (M=32768, N=1024, K=1024), bf16 out
  gemm_bt<1, 1><<<dim3(8, 256, 1), 256, 0, stream>>>(
      textb, Wb, qkv, bias, BB * SEQ, DIM, DIM, 1.0f, 0, 0, 0);
  // 3. qkvT[b] = qkv[b]^T  (for PV as B^T-layout GEMM)
  transpose_bt<<<dim3(16, 16, BB), 256, 0, stream>>>(qkv, qkvT);
  // 4. scores[b] = qkv[b] @ qkv[b]^T / sqrt(D), bf16 out
  gemm_bt<1, 0><<<dim3(8, 8, BB), 256, 0, stream>>>(
      qkv, qkv, sc, nullptr, SEQ, SEQ, DIM, 0.03125f, SSl, SSl, SSl);
  // 5. softmax over batch dim (in-place)
  softmax_b<<<1024, 256, 0, stream>>>(sc);
  // 6. out[b] = attn[b] @ qkv[b]  (B operand via qkvT), fp32 out
  gemm_bt<0, 0><<<dim3(8, 8, BB), 256, 0, stream>>>(
      sc, qkvT, out, nullptr, SEQ, DIM, SEQ, 1.0f, SSl, SSl, SSl);
}

// Round 2
// 389.738 us; speedup vs baseline: 1.1504x; 1.1504x over previous
//
#include <hip/hip_runtime.h>
#include <hip/hip_bf16.h>

typedef __attribute__((ext_vector_type(4))) float f32x4;
typedef __attribute__((ext_vector_type(8))) short short8;

static constexpr int BB = 32;
static constexpr int SEQ = 1024;
static constexpr int DIM = 1024;

__device__ __forceinline__ ushort f2bf(float f) {
  union { float f; uint u; } x; x.f = f;
  uint r = x.u + 0x7fffu + ((x.u >> 16) & 1u);
  return (ushort)(r >> 16);
}
__device__ __forceinline__ float bf2f(ushort h) {
  union { uint u; float f; } x; x.u = ((uint)h) << 16; return x.f;
}

// async global->LDS, 16B per lane. Per-lane global src; LDS dest must be
// wave-uniform base + lane*16 (our addressing satisfies this).
__device__ __forceinline__ void async16(const void* g, void* l) {
  __builtin_amdgcn_global_load_lds(
      (const __attribute__((address_space(1))) unsigned int*)g,
      (__attribute__((address_space(3))) unsigned int*)l, 16, 0, 0);
}

#define SCHED0 __builtin_amdgcn_sched_barrier(0)
#define BAR    __builtin_amdgcn_s_barrier()
#define LGKM0  asm volatile("s_waitcnt lgkmcnt(0)" ::: "memory")

// fp32 -> bf16 elementwise (vectorized by 4)
__global__ void cvt_kernel(const float* __restrict__ in, ushort* __restrict__ out, long n4) {
  long i = (long)blockIdx.x * blockDim.x + threadIdx.x;
  const long stride = (long)gridDim.x * blockDim.x;
  for (; i < n4; i += stride) {
    float4 v = reinterpret_cast<const float4*>(in)[i];
    ushort4 o = make_ushort4(f2bf(v.x), f2bf(v.y), f2bf(v.z), f2bf(v.w));
    reinterpret_cast<ushort4*>(out)[i] = o;
  }
}

// ---------------------------------------------------------------------------
// 256x256-tile, BK=64, 8-wave (2Mx4N), 8-phase-per-2-K-tiles GEMM (T2+T3+T4+T5).
// C[m,n] = scale * sum_k A[m,k]*Bt[n,k] (+ bias[n]); A:[M][K] Bt:[N][K] bf16.
// LDS layout (per buffer, 32KB each for A and B), rows remapped so each
// half-tile (64-row load chunk x2) is contiguous:
//   A lds row r: block row = ((r>>6)&1)*128 + (r>>7)*64 + (r&63)   (mh-major)
//   B lds row r: block col = ((r>>5)&3)*64 + (r>>7)*32 + (r&31)    (nh-major)
// Swizzle st_16x32: byte ^= ((byte>>9)&1)<<5 — applied inverse on the global
// source (linear LDS dest for global_load_lds) and on the ds_read address.
// For frag reads the XOR folds to the per-lane constant (fr&4)<<3.
// ---------------------------------------------------------------------------
template<int OUT_BF16, int HAS_BIAS>
__global__ __launch_bounds__(512, 2)
void gemm256(const ushort* __restrict__ A, const ushort* __restrict__ Bt,
             void* __restrict__ Cv, const float* __restrict__ bias,
             int M, int N, int K, float scale,
             long sA, long sB, long sC)
{
  __shared__ __align__(16) ushort As[2][16384];
  __shared__ __align__(16) ushort Bs[2][16384];

  const int t = threadIdx.x;
  const int z = blockIdx.z;
  const ushort* Ab = A + (long)z * sA;
  const ushort* Bb = Bt + (long)z * sB;
  const int tm = blockIdx.y * 256;
  const int tn = blockIdx.x * 256;

  const int l    = t & 63;
  const int w    = t >> 6;
  const int wrow = w >> 2;       // 0..1
  const int wcol = w & 3;        // 0..3
  const int fr   = l & 15;
  const int g    = l >> 4;       // k-group 0..3
  const int aflip = (fr & 4) << 3;  // swizzle XOR for reads (bit9 == fr bit2)

  f32x4 acc[8][4];
#pragma unroll
  for (int i = 0; i < 8; ++i)
#pragma unroll
    for (int j = 0; j < 4; ++j) acc[i][j] = {0.f, 0.f, 0.f, 0.f};

  short8 a[4][2], b0[2][2], b1[2][2];

  // --- staging: one call = 512 threads x 16B = 8KB = 64 LDS rows ---
  auto stageA = [&](int buf, int R0, int k0) {
    const int P = (R0 << 7) + (t << 4);            // linear LDS byte in As[buf]
    const int L = P ^ (((P >> 9) & 1) << 5);       // logical byte (involution)
    const int lr = L >> 7;
    const int kb = (L & 127) >> 1;
    const int brow = ((lr >> 6) & 1) * 128 + ((lr >> 7) << 6) + (lr & 63);
    async16(Ab + (long)(tm + brow) * K + (k0 + kb), &As[buf][P >> 1]);
  };
  auto stageB = [&](int buf, int R0, int k0) {
    const int P = (R0 << 7) + (t << 4);
    const int L = P ^ (((P >> 9) & 1) << 5);
    const int lr = L >> 7;
    const int kb = (L & 127) >> 1;
    const int bcol = ((lr >> 5) & 3) * 64 + ((lr >> 7) << 5) + (lr & 31);
    async16(Bb + (long)(tn + bcol) * K + (k0 + kb), &Bs[buf][P >> 1]);
  };

  // --- swizzled fragment reads ---
  auto ldA = [&](int buf, int mh, int mi, int ks) -> short8 {
    const int off = (((mh << 7) + (wrow << 6) + (mi << 4) + fr) << 7) + (ks << 6) + (g << 4);
    return *(const short8*)((const char*)As + (buf << 15) + (off ^ aflip));
  };
  auto ldB = [&](int buf, int nh, int ni, int ks) -> short8 {
    const int off = (((nh << 7) + (wcol << 5) + (ni << 4) + fr) << 7) + (ks << 6) + (g << 4);
    return *(const short8*)((const char*)Bs + (buf << 15) + (off ^ aflip));
  };

  const int NKT = K >> 6;  // assumed >= 2 (K=1024 here)

  // --- prologue: kt0 fully (8 loads), kt1 A-a,B-0,B-1 (6 loads) ---
  stageA(0, 0, 0);  stageA(0, 64, 0);
  stageB(0, 0, 0);  stageB(0, 64, 0);
  stageB(0, 128, 0); stageB(0, 192, 0);
  stageA(0, 128, 0); stageA(0, 192, 0);
  if (NKT > 1) {
    stageA(1, 0, 64);  stageA(1, 64, 64);
    stageB(1, 0, 64);  stageB(1, 64, 64);
    stageB(1, 128, 64); stageB(1, 192, 64);
    asm volatile("s_waitcnt vmcnt(6)" ::: "memory");
  } else {
    asm volatile("s_waitcnt vmcnt(0)" ::: "memory");
  }
  SCHED0; BAR;

  for (int kt = 0; kt < NKT; ++kt) {
    const int buf = kt & 1;
    const int k1 = (kt + 1) << 6;
    const int k2 = (kt + 2) << 6;
    const bool s1 = (kt + 1) < NKT;
    const bool s2 = (kt + 2) < NKT;

    // ---- P0: ds-read A(mh0) x8 + B(nh0) x4; stage A-b of kt+1 (other buf)
#pragma unroll
    for (int mi = 0; mi < 4; ++mi) {
      a[mi][0] = ldA(buf, 0, mi, 0);
      a[mi][1] = ldA(buf, 0, mi, 1);
    }
#pragma unroll
    for (int ni = 0; ni < 2; ++ni) {
      b0[ni][0] = ldB(buf, 0, ni, 0);
      b0[ni][1] = ldB(buf, 0, ni, 1);
    }
    if (s1) { stageA(buf ^ 1, 128, k1); stageA(buf ^ 1, 192, k1); }
    SCHED0; BAR; LGKM0; SCHED0;
    __builtin_amdgcn_s_setprio(1);
#pragma unroll
    for (int ks = 0; ks < 2; ++ks)
#pragma unroll
      for (int mi = 0; mi < 4; ++mi)
#pragma unroll
        for (int ni = 0; ni < 2; ++ni)
          acc[mi][ni] = __builtin_amdgcn_mfma_f32_16x16x32_bf16(
              a[mi][ks], b0[ni][ks], acc[mi][ni], 0, 0, 0);
    __builtin_amdgcn_s_setprio(0);
    SCHED0; BAR;

    // ---- P1: ds-read B(nh1) x4; stage A-a of kt+2 (cur buf, region dead after P0)
#pragma unroll
    for (int ni = 0; ni < 2; ++ni) {
      b1[ni][0] = ldB(buf, 1, ni, 0);
      b1[ni][1] = ldB(buf, 1, ni, 1);
    }
    if (s2) { stageA(buf, 0, k2); stageA(buf, 64, k2); }
    SCHED0; BAR; LGKM0; SCHED0;
    __builtin_amdgcn_s_setprio(1);
#pragma unroll
    for (int ks = 0; ks < 2; ++ks)
#pragma unroll
      for (int mi = 0; mi < 4; ++mi)
#pragma unroll
        for (int ni = 0; ni < 2; ++ni)
          acc[mi][2 + ni] = __builtin_amdgcn_mfma_f32_16x16x32_bf16(
              a[mi][ks], b1[ni][ks], acc[mi][2 + ni], 0, 0, 0);
    __builtin_amdgcn_s_setprio(0);
    SCHED0; BAR;

    // ---- P2: ds-read A(mh1) x8 (overwrite a); stage B-0 of kt+2 (dead after P0)
#pragma unroll
    for (int mi = 0; mi < 4; ++mi) {
      a[mi][0] = ldA(buf, 1, mi, 0);
      a[mi][1] = ldA(buf, 1, mi, 1);
    }
    if (s2) { stageB(buf, 0, k2); stageB(buf, 64, k2); }
    SCHED0; BAR; LGKM0; SCHED0;
    __builtin_amdgcn_s_setprio(1);
#pragma unroll
    for (int ks = 0; ks < 2; ++ks)
#pragma unroll
      for (int mi = 0; mi < 4; ++mi)
#pragma unroll
        for (int ni = 0; ni < 2; ++ni)
          acc[4 + mi][ni] = __builtin_amdgcn_mfma_f32_16x16x32_bf16(
              a[mi][ks], b0[ni][ks], acc[4 + mi][ni], 0, 0, 0);
    __builtin_amdgcn_s_setprio(0);
    SCHED0; BAR;

    // ---- P3: no ds-reads; stage B-1 of kt+2 (dead after P1); end-of-tile vmcnt
    if (s2) { stageB(buf, 128, k2); stageB(buf, 192, k2); }
    SCHED0; BAR; SCHED0;
    __builtin_amdgcn_s_setprio(1);
#pragma unroll
    for (int ks = 0; ks < 2; ++ks)
#pragma unroll
      for (int mi = 0; mi < 4; ++mi)
#pragma unroll
        for (int ni = 0; ni < 2; ++ni)
          acc[4 + mi][2 + ni] = __builtin_amdgcn_mfma_f32_16x16x32_bf16(
              a[mi][ks], b1[ni][ks], acc[4 + mi][2 + ni], 0, 0, 0);
    __builtin_amdgcn_s_setprio(0);
    SCHED0;
    if (kt < NKT - 2) {
      asm volatile("s_waitcnt vmcnt(6)" ::: "memory");   // kt+1 fully in LDS
    } else if (kt == NKT - 2) {
      asm volatile("s_waitcnt vmcnt(0)" ::: "memory");   // drain for last tile
    }
    BAR;
  }

  // --- epilogue: C/D layout col=lane&15, row=g*4+reg ---
  const int cr = g * 4;
#pragma unroll
  for (int mi = 0; mi < 8; ++mi) {
#pragma unroll
    for (int ni = 0; ni < 4; ++ni) {
      const int row = tm + wrow * 128 + mi * 16 + cr;
      const int col = tn + wcol * 64 + ni * 16 + fr;
      const float bv = HAS_BIAS ? bias[col] : 0.0f;
#pragma unroll
      for (int r = 0; r < 4; ++r) {
        const float v = acc[mi][ni][r] * scale + bv;
        const long off = (long)z * sC + (long)(row + r) * N + col;
        if (OUT_BF16) ((ushort*)Cv)[off] = f2bf(v);
        else          ((float*)Cv)[off]  = v;
      }
    }
  }
}

// per-batch 64x64-tile bf16 transpose: out[z][d][s] = in[z][s][d]
__global__ void transpose_bt(const ushort* __restrict__ in, ushort* __restrict__ out) {
  const int z = blockIdx.z;
  const long off = (long)z * SEQ * DIM;
  in += off; out += off;
  __shared__ ushort tile[64][68];
  const int t = threadIdx.x;
  const int r0 = blockIdx.y * 64, c0 = blockIdx.x * 64;
  const int tr = t >> 4;
  const int tc = (t & 15) * 4;
#pragma unroll
  for (int it = 0; it < 4; ++it) {
    const int r = tr + it * 16;
    ushort4 v = *(const ushort4*)&in[(long)(r0 + r) * DIM + c0 + tc];
    *(ushort4*)&tile[r][tc] = v;
  }
  __syncthreads();
#pragma unroll
  for (int it = 0; it < 4; ++it) {
    const int dr = tr + it * 16;
    ushort4 v = make_ushort4(tile[tc + 0][dr], tile[tc + 1][dr],
                             tile[tc + 2][dr], tile[tc + 3][dr]);
    *(ushort4*)&out[(long)(c0 + dr) * SEQ + r0 + tc] = v;
  }
}

// softmax over BATCH dim (axis=0): for each (q,k), normalize across 32 batches.
__global__ void softmax_b(ushort* __restrict__ sc) {
  const long SSl = (long)SEQ * SEQ;
  const long e = ((long)blockIdx.x * blockDim.x + threadIdx.x) * 4;
  if (e >= SSl) return;
  uint2 raw[BB];
#pragma unroll
  for (int b = 0; b < BB; ++b) raw[b] = *(const uint2*)&sc[b * SSl + e];
  float mx[4] = {-3.0e38f, -3.0e38f, -3.0e38f, -3.0e38f};
#pragma unroll
  for (int b = 0; b < BB; ++b) {
    const uint lo = raw[b].x, hi = raw[b].y;
    mx[0] = fmaxf(mx[0], bf2f((ushort)(lo & 0xffffu)));
    mx[1] = fmaxf(mx[1], bf2f((ushort)(lo >> 16)));
    mx[2] = fmaxf(mx[2], bf2f((ushort)(hi & 0xffffu)));
    mx[3] = fmaxf(mx[3], bf2f((ushort)(hi >> 16)));
  }
  float sum[4] = {0.f, 0.f, 0.f, 0.f};
#pragma unroll
  for (int b = 0; b < BB; ++b) {
    const uint lo = raw[b].x, hi = raw[b].y;
    const float x0 = __expf(bf2f((ushort)(lo & 0xffffu)) - mx[0]);
    const float x1 = __expf(bf2f((ushort)(lo >> 16))     - mx[1]);
    const float x2 = __expf(bf2f((ushort)(hi & 0xffffu)) - mx[2]);
    const float x3 = __expf(bf2f((ushort)(hi >> 16))     - mx[3]);
    sum[0] += x0; sum[1] += x1; sum[2] += x2; sum[3] += x3;
    raw[b].x = (uint)f2bf(x0) | ((uint)f2bf(x1) << 16);
    raw[b].y = (uint)f2bf(x2) | ((uint)f2bf(x3) << 16);
  }
  const float r0 = 1.0f / sum[0], r1 = 1.0f / sum[1];
  const float r2 = 1.0f / sum[2], r3 = 1.0f / sum[3];
#pragma unroll
  for (int b = 0; b < BB; ++b) {
    const uint lo = raw[b].x, hi = raw[b].y;
    const uint o0 = f2bf(bf2f((ushort)(lo & 0xffffu)) * r0);
    const uint o1 = f2bf(bf2f((ushort)(lo >> 16))     * r1);
    const uint o2 = f2bf(bf2f((ushort)(hi & 0xffffu)) * r2);
    const uint o3 = f2bf(bf2f((ushort)(hi >> 16))     * r3);
    uint2 o; o.x = o0 | (o1 << 16); o.y = o2 | (o3 << 16);
    *(uint2*)&sc[b * SSl + e] = o;
  }
}

extern "C" void kernel_launch(void* const* d_in, const int* in_sizes, int n_in,
                              void* d_out, int out_size, void* d_ws, size_t ws_size,
                              hipStream_t stream) {
  const float* text = (const float*)d_in[0];
  const float* W    = (const float*)d_in[1];
  const float* bias = (const float*)d_in[2];
  float* out = (float*)d_out;

  const long nTxt = (long)BB * SEQ * DIM;   // 33,554,432
  const long nW   = (long)DIM * DIM;        // 1,048,576
  const long SSl  = (long)SEQ * SEQ;        // per-batch score elems

  char* ws = (char*)d_ws;
  ushort* qkv   = (ushort*)ws;                 // 64MB bf16 qkv [B][S][D]
  ushort* qkvT  = (ushort*)(ws + nTxt * 2);    // 64MB bf16 qkv^T [B][D][S]
  ushort* sc    = (ushort*)(ws + nTxt * 4);    // 64MB: text_bf16, then scores/attn
  ushort* textb = sc;                          // alias (text_bf16 dead after GEMM1)
  ushort* Wb    = (ushort*)(ws + nTxt * 6);    // 2MB bf16 W [D][D]
  if (ws_size < (size_t)(nTxt * 6 + nW * 2)) return;  // insufficient scratch

  // 1. convert inputs to bf16
  cvt_kernel<<<2048, 256, 0, stream>>>(text, textb, nTxt / 4);
  cvt_kernel<<<256, 256, 0, stream>>>(W, Wb, nW / 4);
  // 2. qkv = text @ W.T + b   (M=32768, N=1024, K=1024), bf16 out
  gemm256<1, 1><<<dim3(4, 128, 1), 512, 0, stream>>>(
      textb, Wb, qkv, bias, BB * SEQ, DIM, DIM, 1.0f, 0, 0, 0);
  // 3. qkvT[b] = qkv[b]^T  (for PV as B^T-layout GEMM)
  transpose_bt<<<dim3(16, 16, BB), 256, 0, stream>>>(qkv, qkvT);
  // 4. scores[b] = qkv[b] @ qkv[b]^T / sqrt(D), bf16 out
  gemm256<1, 0><<<dim3(4, 4, BB), 512, 0, stream>>>(
      qkv, qkv, sc, nullptr, SEQ, SEQ, DIM, 0.03125f, SSl, SSl, SSl);
  // 5. softmax over batch dim (in-place)
  softmax_b<<<1024, 256, 0, stream>>>(sc);
  // 6. out[b] = attn[b] @ qkv[b]  (B operand via qkvT), fp32 out
  gemm256<0, 0><<<dim3(4, 4, BB), 512, 0, stream>>>(
      sc, qkvT, out, nullptr, SEQ, DIM, SEQ, 1.0f, SSl, SSl, SSl);
}

// Round 3
// 377.204 us; speedup vs baseline: 1.1886x; 1.0332x over previous
//
#include <hip/hip_runtime.h>
#include <hip/hip_bf16.h>

typedef __attribute__((ext_vector_type(4))) float f32x4;
typedef __attribute__((ext_vector_type(8))) short short8;

static constexpr int BB = 32;
static constexpr int SEQ = 1024;
static constexpr int DIM = 1024;

__device__ __forceinline__ ushort f2bf(float f) {
  union { float f; uint u; } x; x.f = f;
  uint r = x.u + 0x7fffu + ((x.u >> 16) & 1u);
  return (ushort)(r >> 16);
}
__device__ __forceinline__ float bf2f(ushort h) {
  union { uint u; float f; } x; x.u = ((uint)h) << 16; return x.f;
}

// async global->LDS, 16B per lane. Per-lane global src; LDS dest must be
// wave-uniform base + lane*16 (our addressing satisfies this).
__device__ __forceinline__ void async16(const void* g, void* l) {
  __builtin_amdgcn_global_load_lds(
      (const __attribute__((address_space(1))) unsigned int*)g,
      (__attribute__((address_space(3))) unsigned int*)l, 16, 0, 0);
}

#define SCHED0 __builtin_amdgcn_sched_barrier(0)
#define BAR    __builtin_amdgcn_s_barrier()
#define LGKM0  asm volatile("s_waitcnt lgkmcnt(0)" ::: "memory")

// fp32 -> bf16 elementwise (vectorized by 4)
__global__ void cvt_kernel(const float* __restrict__ in, ushort* __restrict__ out, long n4) {
  long i = (long)blockIdx.x * blockDim.x + threadIdx.x;
  const long stride = (long)gridDim.x * blockDim.x;
  for (; i < n4; i += stride) {
    float4 v = reinterpret_cast<const float4*>(in)[i];
    ushort4 o = make_ushort4(f2bf(v.x), f2bf(v.y), f2bf(v.z), f2bf(v.w));
    reinterpret_cast<ushort4*>(out)[i] = o;
  }
}

// ---------------------------------------------------------------------------
// 256x256-tile, BK=64, 8-wave (2Mx4N), 4-phase-per-K-tile GEMM (T2+T3+T4+T5).
// C[m,n] = scale * sum_k A[m,k]*Bt[n,k] (+ bias[n]); A:[M][K] Bt:[N][K] bf16.
// LDS rows remapped so each 64-row staging chunk is contiguous:
//   A lds row r: block row = ((r>>6)&1)*128 + (r>>7)*64 + (r&63)   (mh-major)
//   B lds row r: block col = ((r>>5)&3)*64 + (r>>7)*32 + (r&31)    (nh-major)
// Swizzle (G4): byte ^= ((row&7)<<4)  [row = byte>>7] — spreads stride-128B
// frag reads over 8 16B slots. Applied inverse on the global source (LDS dest
// of global_load_lds stays linear) and on the ds_read address (row&7 == fr&7).
// TMODE=1: additionally write transposed bf16 output to Tout[z2][col][row]
// (z2 = row>>10), 8B ushort4 per lane (4 consecutive rows at one col).
// ---------------------------------------------------------------------------
template<int OUT_BF16, int HAS_BIAS, int TMODE>
__global__ __launch_bounds__(512, 2)
void gemm256(const ushort* __restrict__ A, const ushort* __restrict__ Bt,
             void* __restrict__ Cv, const float* __restrict__ bias,
             ushort* __restrict__ Tout,
             int M, int N, int K, float scale,
             long sA, long sB, long sC)
{
  __shared__ __align__(16) ushort As[2][16384];
  __shared__ __align__(16) ushort Bs[2][16384];

  const int t = threadIdx.x;
  const int z = blockIdx.z;
  const ushort* Ab = A + (long)z * sA;
  const ushort* Bb = Bt + (long)z * sB;
  const int tm = blockIdx.y * 256;
  const int tn = blockIdx.x * 256;

  const int l    = t & 63;
  const int w    = t >> 6;
  const int wrow = w >> 2;       // 0..1
  const int wcol = w & 3;        // 0..3
  const int fr   = l & 15;
  const int g    = l >> 4;       // k-group 0..3
  const int aflip = (fr & 7) << 4;  // G4 swizzle XOR for frag reads

  f32x4 acc[8][4];
#pragma unroll
  for (int i = 0; i < 8; ++i)
#pragma unroll
    for (int j = 0; j < 4; ++j) acc[i][j] = {0.f, 0.f, 0.f, 0.f};

  short8 a[4][2], b0[2][2], b1[2][2];

  // --- staging: one call = 512 threads x 16B = 8KB = 64 LDS rows ---
  auto stageA = [&](int buf, int R0, int k0) {
    const int P = (R0 << 7) + (t << 4);            // physical LDS byte
    const int L = P ^ (((P >> 7) & 7) << 4);       // logical byte (involution)
    const int lr = L >> 7;
    const int kb = (L & 127) >> 1;
    const int brow = ((lr >> 6) & 1) * 128 + ((lr >> 7) << 6) + (lr & 63);
    async16(Ab + (long)(tm + brow) * K + (k0 + kb), &As[buf][P >> 1]);
  };
  auto stageB = [&](int buf, int R0, int k0) {
    const int P = (R0 << 7) + (t << 4);
    const int L = P ^ (((P >> 7) & 7) << 4);
    const int lr = L >> 7;
    const int kb = (L & 127) >> 1;
    const int bcol = ((lr >> 5) & 3) * 64 + ((lr >> 7) << 5) + (lr & 31);
    async16(Bb + (long)(tn + bcol) * K + (k0 + kb), &Bs[buf][P >> 1]);
  };

  // --- swizzled fragment reads (row&7 == fr&7 for all frag bases) ---
  auto ldA = [&](int buf, int mh, int mi, int ks) -> short8 {
    const int off = (((mh << 7) + (wrow << 6) + (mi << 4) + fr) << 7) + (ks << 6) + (g << 4);
    return *(const short8*)((const char*)As + (buf << 15) + (off ^ aflip));
  };
  auto ldB = [&](int buf, int nh, int ni, int ks) -> short8 {
    const int off = (((nh << 7) + (wcol << 5) + (ni << 4) + fr) << 7) + (ks << 6) + (g << 4);
    return *(const short8*)((const char*)Bs + (buf << 15) + (off ^ aflip));
  };

  const int NKT = K >> 6;  // >= 2 here (K=1024)

  // --- prologue: kt0 fully (8 loads), kt1 A-a,B-0,B-1 (6 loads) ---
  stageA(0, 0, 0);  stageA(0, 64, 0);
  stageB(0, 0, 0);  stageB(0, 64, 0);
  stageB(0, 128, 0); stageB(0, 192, 0);
  stageA(0, 128, 0); stageA(0, 192, 0);
  if (NKT > 1) {
    stageA(1, 0, 64);  stageA(1, 64, 64);
    stageB(1, 0, 64);  stageB(1, 64, 64);
    stageB(1, 128, 64); stageB(1, 192, 64);
    asm volatile("s_waitcnt vmcnt(6)" ::: "memory");
  } else {
    asm volatile("s_waitcnt vmcnt(0)" ::: "memory");
  }
  SCHED0; BAR;

  for (int kt = 0; kt < NKT; ++kt) {
    const int buf = kt & 1;
    const int k1 = (kt + 1) << 6;
    const int k2 = (kt + 2) << 6;
    const bool s1 = (kt + 1) < NKT;
    const bool s2 = (kt + 2) < NKT;

    // ---- P0: ds-read A(mh0) x8 + B(nh0) x4; stage A-b of kt+1 (other buf)
#pragma unroll
    for (int mi = 0; mi < 4; ++mi) {
      a[mi][0] = ldA(buf, 0, mi, 0);
      a[mi][1] = ldA(buf, 0, mi, 1);
    }
#pragma unroll
    for (int ni = 0; ni < 2; ++ni) {
      b0[ni][0] = ldB(buf, 0, ni, 0);
      b0[ni][1] = ldB(buf, 0, ni, 1);
    }
    if (s1) { stageA(buf ^ 1, 128, k1); stageA(buf ^ 1, 192, k1); }
    SCHED0; BAR; LGKM0; SCHED0;
    __builtin_amdgcn_s_setprio(1);
#pragma unroll
    for (int ks = 0; ks < 2; ++ks)
#pragma unroll
      for (int mi = 0; mi < 4; ++mi)
#pragma unroll
        for (int ni = 0; ni < 2; ++ni)
          acc[mi][ni] = __builtin_amdgcn_mfma_f32_16x16x32_bf16(
              a[mi][ks], b0[ni][ks], acc[mi][ni], 0, 0, 0);
    __builtin_amdgcn_s_setprio(0);
    SCHED0; BAR;

    // ---- P1: ds-read B(nh1) x4; stage A-a of kt+2 (cur buf, region dead after P0)
#pragma unroll
    for (int ni = 0; ni < 2; ++ni) {
      b1[ni][0] = ldB(buf, 1, ni, 0);
      b1[ni][1] = ldB(buf, 1, ni, 1);
    }
    if (s2) { stageA(buf, 0, k2); stageA(buf, 64, k2); }
    SCHED0; BAR; LGKM0; SCHED0;
    __builtin_amdgcn_s_setprio(1);
#pragma unroll
    for (int ks = 0; ks < 2; ++ks)
#pragma unroll
      for (int mi = 0; mi < 4; ++mi)
#pragma unroll
        for (int ni = 0; ni < 2; ++ni)
          acc[mi][2 + ni] = __builtin_amdgcn_mfma_f32_16x16x32_bf16(
              a[mi][ks], b1[ni][ks], acc[mi][2 + ni], 0, 0, 0);
    __builtin_amdgcn_s_setprio(0);
    SCHED0; BAR;

    // ---- P2: ds-read A(mh1) x8 (overwrite a); stage B-0 of kt+2 (dead after P0)
#pragma unroll
    for (int mi = 0; mi < 4; ++mi) {
      a[mi][0] = ldA(buf, 1, mi, 0);
      a[mi][1] = ldA(buf, 1, mi, 1);
    }
    if (s2) { stageB(buf, 0, k2); stageB(buf, 64, k2); }
    SCHED0; BAR; LGKM0; SCHED0;
    __builtin_amdgcn_s_setprio(1);
#pragma unroll
    for (int ks = 0; ks < 2; ++ks)
#pragma unroll
      for (int mi = 0; mi < 4; ++mi)
#pragma unroll
        for (int ni = 0; ni < 2; ++ni)
          acc[4 + mi][ni] = __builtin_amdgcn_mfma_f32_16x16x32_bf16(
              a[mi][ks], b0[ni][ks], acc[4 + mi][ni], 0, 0, 0);
    __builtin_amdgcn_s_setprio(0);
    SCHED0; BAR;

    // ---- P3: no ds-reads; stage B-1 of kt+2 (dead after P1); end-of-tile vmcnt
    if (s2) { stageB(buf, 128, k2); stageB(buf, 192, k2); }
    SCHED0; BAR; SCHED0;
    __builtin_amdgcn_s_setprio(1);
#pragma unroll
    for (int ks = 0; ks < 2; ++ks)
#pragma unroll
      for (int mi = 0; mi < 4; ++mi)
#pragma unroll
        for (int ni = 0; ni < 2; ++ni)
          acc[4 + mi][2 + ni] = __builtin_amdgcn_mfma_f32_16x16x32_bf16(
              a[mi][ks], b1[ni][ks], acc[4 + mi][2 + ni], 0, 0, 0);
    __builtin_amdgcn_s_setprio(0);
    SCHED0;
    if (kt < NKT - 2) {
      asm volatile("s_waitcnt vmcnt(6)" ::: "memory");   // kt+1 fully in LDS
    } else if (kt == NKT - 2) {
      asm volatile("s_waitcnt vmcnt(0)" ::: "memory");   // drain for last tile
    }
    BAR;
  }

  // --- epilogue: C/D layout col=lane&15, row=g*4+reg ---
  const int cr = g * 4;
#pragma unroll
  for (int mi = 0; mi < 8; ++mi) {
#pragma unroll
    for (int ni = 0; ni < 4; ++ni) {
      const int row = tm + wrow * 128 + mi * 16 + cr;
      const int col = tn + wcol * 64 + ni * 16 + fr;
      const float bv = HAS_BIAS ? bias[col] : 0.0f;
      float v[4];
#pragma unroll
      for (int r = 0; r < 4; ++r) v[r] = acc[mi][ni][r] * scale + bv;
#pragma unroll
      for (int r = 0; r < 4; ++r) {
        const long off = (long)z * sC + (long)(row + r) * N + col;
        if (OUT_BF16) ((ushort*)Cv)[off] = f2bf(v[r]);
        else          ((float*)Cv)[off]  = v[r];
      }
      if (TMODE) {  // transposed copy: Tout[z2][col][row..row+3], z2 = row>>10
        ushort4 o = make_ushort4(f2bf(v[0]), f2bf(v[1]), f2bf(v[2]), f2bf(v[3]));
        const long ti = ((long)(row >> 10) << 20) + ((long)col << 10) + (row & 1023);
        *(ushort4*)&Tout[ti] = o;
      }
    }
  }
}

// softmax over BATCH dim (axis=0): for each (q,k), normalize across 32 batches.
__global__ void softmax_b(ushort* __restrict__ sc) {
  const long SSl = (long)SEQ * SEQ;
  const long e = ((long)blockIdx.x * blockDim.x + threadIdx.x) * 4;
  if (e >= SSl) return;
  uint2 raw[BB];
#pragma unroll
  for (int b = 0; b < BB; ++b) raw[b] = *(const uint2*)&sc[b * SSl + e];
  float mx[4] = {-3.0e38f, -3.0e38f, -3.0e38f, -3.0e38f};
#pragma unroll
  for (int b = 0; b < BB; ++b) {
    const uint lo = raw[b].x, hi = raw[b].y;
    mx[0] = fmaxf(mx[0], bf2f((ushort)(lo & 0xffffu)));
    mx[1] = fmaxf(mx[1], bf2f((ushort)(lo >> 16)));
    mx[2] = fmaxf(mx[2], bf2f((ushort)(hi & 0xffffu)));
    mx[3] = fmaxf(mx[3], bf2f((ushort)(hi >> 16)));
  }
  float sum[4] = {0.f, 0.f, 0.f, 0.f};
#pragma unroll
  for (int b = 0; b < BB; ++b) {
    const uint lo = raw[b].x, hi = raw[b].y;
    const float x0 = __expf(bf2f((ushort)(lo & 0xffffu)) - mx[0]);
    const float x1 = __expf(bf2f((ushort)(lo >> 16))     - mx[1]);
    const float x2 = __expf(bf2f((ushort)(hi & 0xffffu)) - mx[2]);
    const float x3 = __expf(bf2f((ushort)(hi >> 16))     - mx[3]);
    sum[0] += x0; sum[1] += x1; sum[2] += x2; sum[3] += x3;
    raw[b].x = (uint)f2bf(x0) | ((uint)f2bf(x1) << 16);
    raw[b].y = (uint)f2bf(x2) | ((uint)f2bf(x3) << 16);
  }
  const float r0 = 1.0f / sum[0], r1 = 1.0f / sum[1];
  const float r2 = 1.0f / sum[2], r3 = 1.0f / sum[3];
#pragma unroll
  for (int b = 0; b < BB; ++b) {
    const uint lo = raw[b].x, hi = raw[b].y;
    const uint o0 = f2bf(bf2f((ushort)(lo & 0xffffu)) * r0);
    const uint o1 = f2bf(bf2f((ushort)(lo >> 16))     * r1);
    const uint o2 = f2bf(bf2f((ushort)(hi & 0xffffu)) * r2);
    const uint o3 = f2bf(bf2f((ushort)(hi >> 16))     * r3);
    uint2 o; o.x = o0 | (o1 << 16); o.y = o2 | (o3 << 16);
    *(uint2*)&sc[b * SSl + e] = o;
  }
}

extern "C" void kernel_launch(void* const* d_in, const int* in_sizes, int n_in,
                              void* d_out, int out_size, void* d_ws, size_t ws_size,
                              hipStream_t stream) {
  const float* text = (const float*)d_in[0];
  const float* W    = (const float*)d_in[1];
  const float* bias = (const float*)d_in[2];
  float* out = (float*)d_out;

  const long nTxt = (long)BB * SEQ * DIM;   // 33,554,432
  const long nW   = (long)DIM * DIM;        // 1,048,576
  const long SSl  = (long)SEQ * SEQ;        // per-batch score elems

  char* ws = (char*)d_ws;
  ushort* qkv   = (ushort*)ws;                 // 64MB bf16 qkv [B][S][D]
  ushort* qkvT  = (ushort*)(ws + nTxt * 2);    // 64MB bf16 qkv^T [B][D][S]
  ushort* sc    = (ushort*)(ws + nTxt * 4);    // 64MB: text_bf16, then scores/attn
  ushort* textb = sc;                          // alias (text_bf16 dead after GEMM1)
  ushort* Wb    = (ushort*)(ws + nTxt * 6);    // 2MB bf16 W [D][D]
  if (ws_size < (size_t)(nTxt * 6 + nW * 2)) return;  // insufficient scratch

  // 1. convert inputs to bf16
  cvt_kernel<<<2048, 256, 0, stream>>>(text, textb, nTxt / 4);
  cvt_kernel<<<256, 256, 0, stream>>>(W, Wb, nW / 4);
  // 2. qkv = text @ W.T + b  (M=32768,N=1024,K=1024); also writes qkvT fused
  gemm256<1, 1, 1><<<dim3(4, 128, 1), 512, 0, stream>>>(
      textb, Wb, qkv, bias, qkvT, BB * SEQ, DIM, DIM, 1.0f, 0, 0, 0);
  // 3. scores[b] = qkv[b] @ qkv[b]^T / sqrt(D), bf16 out
  gemm256<1, 0, 0><<<dim3(4, 4, BB), 512, 0, stream>>>(
      qkv, qkv, sc, nullptr, nullptr, SEQ, SEQ, DIM, 0.03125f, SSl, SSl, SSl);
  // 4. softmax over batch dim (in-place)
  softmax_b<<<1024, 256, 0, stream>>>(sc);
  // 5. out[b] = attn[b] @ qkv[b]  (B operand via qkvT), fp32 out
  gemm256<0, 0, 0><<<dim3(4, 4, BB), 512, 0, stream>>>(
      sc, qkvT, out, nullptr, nullptr, SEQ, DIM, SEQ, 1.0f, SSl, SSl, SSl);
}